// Round 1
// baseline (569.331 us; speedup 1.0000x reference)
//
#include <hip/hip_runtime.h>

typedef unsigned int uint;

#define NHALF 2048
#define DIM   1024
#define MROWS 4096
#define NTOT  (16777216ull)     // 4096*4096
#define NF4   (4194304ull)      // NTOT/4
#define KMED  8388607u          // (NTOT-1)/2

// workspace layout (bytes)
#define L2_OFF   0ull
#define SQ_OFF   67108864ull                 // 4096*4096*4
#define HIST_OFF (SQ_OFF + 16384ull)         // 4096 floats sq
#define SEL_OFF  (HIST_OFF + 4096ull)        // 4 passes * 256 uints
#define ACC_OFF  (SEL_OFF + 32ull)

// ---------------------------------------------------------------- sqnorm
__global__ __launch_bounds__(256) void sqnorm_kernel(const float* __restrict__ src,
                                                     const float* __restrict__ tgt,
                                                     float* __restrict__ sq) {
    int row = blockIdx.x;
    const float* p = (row < NHALF) ? src + (size_t)row * DIM
                                   : tgt + (size_t)(row - NHALF) * DIM;
    int t = threadIdx.x;
    float4 v = reinterpret_cast<const float4*>(p)[t];   // 256*4 = 1024
    float s = v.x * v.x + v.y * v.y + v.z * v.z + v.w * v.w;
    for (int o = 32; o; o >>= 1) s += __shfl_down(s, o);
    __shared__ float red[4];
    if ((t & 63) == 0) red[t >> 6] = s;
    __syncthreads();
    if (t == 0) sq[row] = red[0] + red[1] + red[2] + red[3];
}

// ---------------------------------------------------------------- L2 = sq_i + sq_j - 2 A A^T  (f32, symmetric)
#define BT 128
#define TK 16
__global__ __launch_bounds__(256) void l2_kernel(const float* __restrict__ src,
                                                 const float* __restrict__ tgt,
                                                 const float* __restrict__ sq,
                                                 float* __restrict__ L2) {
    int bi = blockIdx.y, bj = blockIdx.x;
    if (bj > bi) return;                       // symmetry: lower triangle only
    __shared__ float As[TK][BT + 4];
    __shared__ float Bs[TK][BT + 4];
    const float* Ab = (bi * BT < NHALF) ? src + (size_t)bi * BT * DIM
                                        : tgt + ((size_t)bi * BT - NHALF) * DIM;
    const float* Bb = (bj * BT < NHALF) ? src + (size_t)bj * BT * DIM
                                        : tgt + ((size_t)bj * BT - NHALF) * DIM;
    int t  = threadIdx.x;
    int tx = t & 15, ty = t >> 4;
    // global-load mapping: float4 q = t and t+256; row = q>>2, col4 = (q&3)*4
    int r0 = t >> 2;              // 0..63
    int c0 = (t & 3) * 4;         // 0,4,8,12
    int r1 = r0 + 64;             // 64..127

    float acc[8][8] = {};
    for (int k0 = 0; k0 < DIM; k0 += TK) {
        float4 a0 = *reinterpret_cast<const float4*>(Ab + (size_t)r0 * DIM + k0 + c0);
        float4 a1 = *reinterpret_cast<const float4*>(Ab + (size_t)r1 * DIM + k0 + c0);
        float4 b0 = *reinterpret_cast<const float4*>(Bb + (size_t)r0 * DIM + k0 + c0);
        float4 b1 = *reinterpret_cast<const float4*>(Bb + (size_t)r1 * DIM + k0 + c0);
        __syncthreads();           // previous iter's readers done
        As[c0 + 0][r0] = a0.x; As[c0 + 1][r0] = a0.y; As[c0 + 2][r0] = a0.z; As[c0 + 3][r0] = a0.w;
        As[c0 + 0][r1] = a1.x; As[c0 + 1][r1] = a1.y; As[c0 + 2][r1] = a1.z; As[c0 + 3][r1] = a1.w;
        Bs[c0 + 0][r0] = b0.x; Bs[c0 + 1][r0] = b0.y; Bs[c0 + 2][r0] = b0.z; Bs[c0 + 3][r0] = b0.w;
        Bs[c0 + 0][r1] = b1.x; Bs[c0 + 1][r1] = b1.y; Bs[c0 + 2][r1] = b1.z; Bs[c0 + 3][r1] = b1.w;
        __syncthreads();
#pragma unroll
        for (int kk = 0; kk < TK; ++kk) {
            float a[8], b[8];
            *reinterpret_cast<float4*>(&a[0]) = *reinterpret_cast<const float4*>(&As[kk][ty * 8]);
            *reinterpret_cast<float4*>(&a[4]) = *reinterpret_cast<const float4*>(&As[kk][ty * 8 + 4]);
            *reinterpret_cast<float4*>(&b[0]) = *reinterpret_cast<const float4*>(&Bs[kk][tx * 8]);
            *reinterpret_cast<float4*>(&b[4]) = *reinterpret_cast<const float4*>(&Bs[kk][tx * 8 + 4]);
#pragma unroll
            for (int r = 0; r < 8; ++r)
#pragma unroll
                for (int c = 0; c < 8; ++c) acc[r][c] += a[r] * b[c];
        }
    }
    int gi0 = bi * BT + ty * 8;
    int gj0 = bj * BT + tx * 8;
    float sqi[8], sqj[8];
#pragma unroll
    for (int r = 0; r < 8; ++r) sqi[r] = sq[gi0 + r];
#pragma unroll
    for (int c = 0; c < 8; ++c) sqj[c] = sq[gj0 + c];
#pragma unroll
    for (int r = 0; r < 8; ++r) {
#pragma unroll
        for (int c = 0; c < 8; ++c) {
            float v = fmaxf(sqi[r] + sqj[c] - 2.0f * acc[r][c], 0.0f);
            L2[(size_t)(gi0 + r) * MROWS + (gj0 + c)] = v;
            L2[(size_t)(gj0 + c) * MROWS + (gi0 + r)] = v;
        }
    }
}

// ---------------------------------------------------------------- radix-select histogram (8 bits/pass)
__global__ __launch_bounds__(256) void hist_kernel(const float* __restrict__ L2,
                                                   uint* __restrict__ hist,
                                                   const uint* __restrict__ sel,
                                                   int pass) {
    int shift = 24 - 8 * pass;
    uint prefix = (pass == 0) ? 0u : sel[0];
    uint maskhi = (pass == 0) ? 0u : (0xFFFFFFFFu << (shift + 8));
    __shared__ uint h[256 * 4];                 // 4 replicas vs hot-bin serialization
    for (int i = threadIdx.x; i < 1024; i += 256) h[i] = 0;
    __syncthreads();
    int rep = threadIdx.x & 3;
    size_t stride = (size_t)gridDim.x * blockDim.x;
    for (size_t q = (size_t)blockIdx.x * blockDim.x + threadIdx.x; q < NF4; q += stride) {
        float4 v = reinterpret_cast<const float4*>(L2)[q];
        uint b0 = __float_as_uint(v.x), b1 = __float_as_uint(v.y);
        uint b2 = __float_as_uint(v.z), b3 = __float_as_uint(v.w);
        if ((b0 & maskhi) == prefix) atomicAdd(&h[(((b0 >> shift) & 0xFF) << 2) + rep], 1u);
        if ((b1 & maskhi) == prefix) atomicAdd(&h[(((b1 >> shift) & 0xFF) << 2) + rep], 1u);
        if ((b2 & maskhi) == prefix) atomicAdd(&h[(((b2 >> shift) & 0xFF) << 2) + rep], 1u);
        if ((b3 & maskhi) == prefix) atomicAdd(&h[(((b3 >> shift) & 0xFF) << 2) + rep], 1u);
    }
    __syncthreads();
    uint tot = h[threadIdx.x * 4] + h[threadIdx.x * 4 + 1] + h[threadIdx.x * 4 + 2] + h[threadIdx.x * 4 + 3];
    if (tot) atomicAdd(&hist[threadIdx.x], tot);
}

// ---------------------------------------------------------------- select the radix bucket
__global__ void select_kernel(const uint* __restrict__ hist, uint* __restrict__ sel,
                              float* __restrict__ out, int pass) {
    __shared__ uint h[256];
    h[threadIdx.x] = hist[threadIdx.x];
    __syncthreads();
    if (threadIdx.x != 0) return;
    uint k      = (pass == 0) ? KMED : sel[1];
    uint prefix = (pass == 0) ? 0u   : sel[0];
    int shift = 24 - 8 * pass;
    uint cum = 0;
    int b = 0;
    for (; b < 256; ++b) {
        uint c = h[b];
        if (cum + c > k) break;
        cum += c;
    }
    prefix |= ((uint)b) << shift;
    sel[0] = prefix;
    sel[1] = k - cum;
    if (pass == 3) {
        float median = __uint_as_float(prefix);
        float logn = logf(2048.0f + 1e-8f);
        float bw = sqrtf(0.5f * median / logn);
        out[1] = bw;                               // bandwidth
        reinterpret_cast<float*>(sel)[2] = logn / median;   // 1/(2 bw^2)
    }
}

// ---------------------------------------------------------------- loss reduce
__global__ __launch_bounds__(256) void loss_kernel(const float* __restrict__ L2,
                                                   const float* __restrict__ selF,
                                                   double* __restrict__ acc) {
    float itb = selF[2];            // 1/(2 bw^2)
    int t = threadIdx.x;
    float local = 0.0f;
    size_t stride = (size_t)gridDim.x * blockDim.x;
    for (size_t q = (size_t)blockIdx.x * blockDim.x + t; q < NF4; q += stride) {
        size_t idx = q * 4;
        int i = (int)(idx >> 12);
        int j = (int)(idx & 4095);
        float sgn = ((i < NHALF) == (j < NHALF)) ? 1.0f : -1.0f;
        float4 v = reinterpret_cast<const float4*>(L2)[q];
        float s = __expf(-v.x * itb) + __expf(-v.y * itb) + __expf(-v.z * itb) + __expf(-v.w * itb);
        local += sgn * s;
    }
    for (int o = 32; o; o >>= 1) local += __shfl_down(local, o);
    __shared__ float red[4];
    if ((t & 63) == 0) red[t >> 6] = local;
    __syncthreads();
    if (t == 0) atomicAdd(acc, (double)(red[0] + red[1] + red[2] + red[3]));
}

__global__ void finalize_kernel(const double* __restrict__ acc, float* __restrict__ out) {
    out[0] = (float)(acc[0] / 4194304.0);       // mean over N*N, N=2048
}

// ---------------------------------------------------------------- launch
extern "C" void kernel_launch(void* const* d_in, const int* in_sizes, int n_in,
                              void* d_out, int out_size, void* d_ws, size_t ws_size,
                              hipStream_t stream) {
    const float* src = (const float*)d_in[0];
    const float* tgt = (const float*)d_in[1];
    float* out = (float*)d_out;
    char* ws = (char*)d_ws;
    float*  L2   = (float*)(ws + L2_OFF);
    float*  sq   = (float*)(ws + SQ_OFF);
    uint*   hist = (uint*)(ws + HIST_OFF);
    uint*   sel  = (uint*)(ws + SEL_OFF);
    double* acc  = (double*)(ws + ACC_OFF);

    // zero hist (4KB) + sel (32B) + acc (16B)
    hipMemsetAsync(ws + HIST_OFF, 0, 4096 + 32 + 16, stream);

    sqnorm_kernel<<<MROWS, 256, 0, stream>>>(src, tgt, sq);

    dim3 grid(MROWS / BT, MROWS / BT);
    l2_kernel<<<grid, 256, 0, stream>>>(src, tgt, sq, L2);

    for (int p = 0; p < 4; ++p) {
        hist_kernel<<<2048, 256, 0, stream>>>(L2, hist + p * 256, sel, p);
        select_kernel<<<1, 256, 0, stream>>>(hist + p * 256, sel, out, p);
    }

    loss_kernel<<<2048, 256, 0, stream>>>(L2, (const float*)sel, acc);
    finalize_kernel<<<1, 1, 0, stream>>>(acc, out);
}

// Round 2
// 252.286 us; speedup vs baseline: 2.2567x; 2.2567x over previous
//
#include <hip/hip_runtime.h>

typedef unsigned int uint;
typedef unsigned short ushort;
using short8 = __attribute__((ext_vector_type(8))) short;   // 8 bf16 (4 VGPRs)
using f32x4  = __attribute__((ext_vector_type(4))) float;

#define NHALF 2048
#define DIM   1024
#define MROWS 4096
#define NTOT  16777216ull
#define KMED  8388607u
#define NTRI  528            // 32*33/2 lower-triangle 128x128 blocks

// workspace layout (bytes)
#define L2_OFF   0ull                          // 64 MB f32 (lower blocks valid only)
#define AH_OFF   67108864ull                   // 8 MB bf16 hi
#define AL_OFF   (AH_OFF + 8388608ull)         // 8 MB bf16 lo
#define SQ_OFF   (AL_OFF + 8388608ull)         // 16 KB sq norms
#define HIST_OFF (SQ_OFF + 16384ull)           // 4 KB (4 passes x 256)
#define SEL_OFF  (HIST_OFF + 4096ull)          // 32 B
#define ACC_OFF  (SEL_OFF + 32ull)             // 16 B

// ---------------------------------------------------------------- f32 -> bf16 hi/lo split + sqnorm
__device__ __forceinline__ ushort f2bf(float x) {
    uint u = __float_as_uint(x);
    u += 0x7FFFu + ((u >> 16) & 1u);           // RNE
    return (ushort)(u >> 16);
}

__global__ __launch_bounds__(256) void convert_kernel(const float* __restrict__ src,
                                                      const float* __restrict__ tgt,
                                                      ushort* __restrict__ ah,
                                                      ushort* __restrict__ al,
                                                      float* __restrict__ sq) {
    int row = blockIdx.x;
    const float* p = (row < NHALF) ? src + (size_t)row * DIM
                                   : tgt + (size_t)(row - NHALF) * DIM;
    int t = threadIdx.x;
    float4 v = reinterpret_cast<const float4*>(p)[t];
    float xs[4] = {v.x, v.y, v.z, v.w};
    ushort hh[4], ll[4];
    float s = 0.0f;
#pragma unroll
    for (int e = 0; e < 4; ++e) {
        float x = xs[e];
        s += x * x;
        ushort hb = f2bf(x);
        float hf = __uint_as_float(((uint)hb) << 16);
        ll[e] = f2bf(x - hf);
        hh[e] = hb;
    }
    ushort4 h4; h4.x = hh[0]; h4.y = hh[1]; h4.z = hh[2]; h4.w = hh[3];
    ushort4 l4; l4.x = ll[0]; l4.y = ll[1]; l4.z = ll[2]; l4.w = ll[3];
    reinterpret_cast<ushort4*>(ah + (size_t)row * DIM)[t] = h4;
    reinterpret_cast<ushort4*>(al + (size_t)row * DIM)[t] = l4;
    for (int o = 32; o; o >>= 1) s += __shfl_down(s, o);
    __shared__ float red[4];
    if ((t & 63) == 0) red[t >> 6] = s;
    __syncthreads();
    if (t == 0) sq[row] = red[0] + red[1] + red[2] + red[3];
}

// ---------------------------------------------------------------- MFMA GEMM (bf16-split), lower triangle
// stage one 16B chunk per lane via global_load_lds; LDS dest = uniform base + lane*16
#define STAGE(dst, srcp, rb, bidx) do {                                                   \
    int _i = (bidx) + lane;                                                               \
    const ushort* _g = (srcp) + ((size_t)((rb) + (_i >> 2)) * DIM + k0 + (_i & 3) * 8);   \
    __builtin_amdgcn_global_load_lds(                                                     \
        (const __attribute__((address_space(1))) uint*)_g,                                \
        (__attribute__((address_space(3))) uint*)(&dst[0][0] + (size_t)(bidx) * 8),       \
        16, 0, 0);                                                                        \
} while (0)

__global__ __launch_bounds__(256) void gemm_kernel(const ushort* __restrict__ ah,
                                                   const ushort* __restrict__ al,
                                                   const float* __restrict__ sq,
                                                   float* __restrict__ L2) {
    // XCD swizzle (528 = 8*66, bijective) then triangular decode
    int b = (int)blockIdx.x;
    b = (b & 7) * 66 + (b >> 3);
    int bi = (int)((sqrtf(8.0f * (float)b + 1.0f) - 1.0f) * 0.5f);
    while ((bi + 1) * (bi + 2) / 2 <= b) ++bi;
    while (bi * (bi + 1) / 2 > b) --bi;
    int bj = b - bi * (bi + 1) / 2;          // bj <= bi

    __shared__ __align__(16) ushort Ah[128][32];
    __shared__ __align__(16) ushort Al[128][32];
    __shared__ __align__(16) ushort Bh[128][32];
    __shared__ __align__(16) ushort Bl[128][32];

    int t = threadIdx.x;
    int lane = t & 63, wid = t >> 6;
    int wm = wid >> 1, wn = wid & 1;         // 2x2 wave grid, 64x64 per wave
    int rowbase = bi * 128, colbase = bj * 128;

    f32x4 acc[4][4] = {};
    int fr = lane & 15, fk = (lane >> 4) * 8;

    for (int k0 = 0; k0 < DIM; k0 += 32) {
        __syncthreads();                      // prev-iter readers done
        STAGE(Ah, ah, rowbase, wid * 128);
        STAGE(Ah, ah, rowbase, wid * 128 + 64);
        STAGE(Al, al, rowbase, wid * 128);
        STAGE(Al, al, rowbase, wid * 128 + 64);
        STAGE(Bh, ah, colbase, wid * 128);
        STAGE(Bh, ah, colbase, wid * 128 + 64);
        STAGE(Bl, al, colbase, wid * 128);
        STAGE(Bl, al, colbase, wid * 128 + 64);
        __syncthreads();                      // barrier drains vmcnt -> tiles ready

        short8 fah[4], fal[4], fbh[4], fbl[4];
#pragma unroll
        for (int m = 0; m < 4; ++m) {
            fah[m] = *reinterpret_cast<const short8*>(&Ah[wm * 64 + m * 16 + fr][fk]);
            fal[m] = *reinterpret_cast<const short8*>(&Al[wm * 64 + m * 16 + fr][fk]);
        }
#pragma unroll
        for (int n = 0; n < 4; ++n) {
            fbh[n] = *reinterpret_cast<const short8*>(&Bh[wn * 64 + n * 16 + fr][fk]);
            fbl[n] = *reinterpret_cast<const short8*>(&Bl[wn * 64 + n * 16 + fr][fk]);
        }
#pragma unroll
        for (int m = 0; m < 4; ++m)
#pragma unroll
            for (int n = 0; n < 4; ++n) {
                acc[m][n] = __builtin_amdgcn_mfma_f32_16x16x32_bf16(fah[m], fbh[n], acc[m][n], 0, 0, 0);
                acc[m][n] = __builtin_amdgcn_mfma_f32_16x16x32_bf16(fah[m], fbl[n], acc[m][n], 0, 0, 0);
                acc[m][n] = __builtin_amdgcn_mfma_f32_16x16x32_bf16(fal[m], fbh[n], acc[m][n], 0, 0, 0);
            }
    }

    // epilogue: L2 = max(sq_i + sq_j - 2*dot, 0); lower blocks only, no mirror
    int fq = lane >> 4;
#pragma unroll
    for (int m = 0; m < 4; ++m) {
#pragma unroll
        for (int n = 0; n < 4; ++n) {
            int gj = colbase + wn * 64 + n * 16 + fr;
            float sqj = sq[gj];
#pragma unroll
            for (int r = 0; r < 4; ++r) {
                int gi = rowbase + wm * 64 + m * 16 + fq * 4 + r;
                float v = fmaxf(sq[gi] + sqj - 2.0f * acc[m][n][r], 0.0f);
                L2[(size_t)gi * MROWS + gj] = v;
            }
        }
    }
}

// ---------------------------------------------------------------- radix-select histogram over triangle
__global__ __launch_bounds__(256) void hist_kernel(const float* __restrict__ L2,
                                                   uint* __restrict__ hist,
                                                   const uint* __restrict__ sel,
                                                   int pass) {
    int shift = 24 - 8 * pass;
    uint prefix = (pass == 0) ? 0u : sel[0];
    uint maskhi = (pass == 0) ? 0u : (0xFFFFFFFFu << (shift + 8));
    __shared__ uint h[1024];                   // 4 replicas
    for (int i = threadIdx.x; i < 1024; i += 256) h[i] = 0;
    __syncthreads();
    int rep = threadIdx.x & 3;
    for (int row = blockIdx.x; row < MROWS; row += gridDim.x) {
        int nc = ((row >> 7) + 1) << 7;        // valid cols for this row
        int diaglo = (row >> 7) << 7;          // diagonal-block start
        const float4* rp = reinterpret_cast<const float4*>(L2 + (size_t)row * MROWS);
        for (int q = threadIdx.x; q < (nc >> 2); q += 256) {
            float4 v = rp[q];
            uint w = ((q << 2) >= diaglo) ? 1u : 2u;   // float4 never crosses a 128-col block
            uint bb[4] = {__float_as_uint(v.x), __float_as_uint(v.y),
                          __float_as_uint(v.z), __float_as_uint(v.w)};
#pragma unroll
            for (int e = 0; e < 4; ++e)
                if ((bb[e] & maskhi) == prefix)
                    atomicAdd(&h[(((bb[e] >> shift) & 0xFF) << 2) + rep], w);
        }
    }
    __syncthreads();
    uint tot = h[threadIdx.x * 4] + h[threadIdx.x * 4 + 1] +
               h[threadIdx.x * 4 + 2] + h[threadIdx.x * 4 + 3];
    if (tot) atomicAdd(&hist[threadIdx.x], tot);
}

// ---------------------------------------------------------------- select radix bucket
__global__ void select_kernel(const uint* __restrict__ hist, uint* __restrict__ sel,
                              float* __restrict__ out, int pass) {
    __shared__ uint h[256];
    h[threadIdx.x] = hist[threadIdx.x];
    __syncthreads();
    if (threadIdx.x != 0) return;
    uint k      = (pass == 0) ? KMED : sel[1];
    uint prefix = (pass == 0) ? 0u   : sel[0];
    int shift = 24 - 8 * pass;
    uint cum = 0;
    int b = 0;
    for (; b < 256; ++b) {
        uint c = h[b];
        if (cum + c > k) break;
        cum += c;
    }
    prefix |= ((uint)b) << shift;
    sel[0] = prefix;
    sel[1] = k - cum;
    if (pass == 3) {
        float median = __uint_as_float(prefix);
        float logn = logf(2048.0f + 1e-8f);
        float bw = sqrtf(0.5f * median / logn);
        out[1] = bw;                                      // bandwidth
        reinterpret_cast<float*>(sel)[2] = logn / median; // 1/(2 bw^2)
    }
}

// ---------------------------------------------------------------- loss reduce over triangle (weighted)
__global__ __launch_bounds__(256) void loss_kernel(const float* __restrict__ L2,
                                                   const float* __restrict__ selF,
                                                   double* __restrict__ acc) {
    float itb = selF[2];                       // 1/(2 bw^2)
    int t = threadIdx.x;
    float local = 0.0f;
    for (int row = blockIdx.x; row < MROWS; row += gridDim.x) {
        int nc = ((row >> 7) + 1) << 7;
        int diaglo = (row >> 7) << 7;
        bool rlow = row < NHALF;
        const float4* rp = reinterpret_cast<const float4*>(L2 + (size_t)row * MROWS);
        for (int q = t; q < (nc >> 2); q += 256) {
            float4 v = rp[q];
            int j0 = q << 2;
            float w = (j0 >= diaglo) ? 1.0f : 2.0f;
            float sgn = ((j0 < NHALF) == rlow) ? w : -w;   // NHALF is 128-block aligned
            float s = __expf(-v.x * itb) + __expf(-v.y * itb) +
                      __expf(-v.z * itb) + __expf(-v.w * itb);
            local += sgn * s;
        }
    }
    for (int o = 32; o; o >>= 1) local += __shfl_down(local, o);
    __shared__ float red[4];
    if ((t & 63) == 0) red[t >> 6] = local;
    __syncthreads();
    if (t == 0) atomicAdd(acc, (double)(red[0] + red[1] + red[2] + red[3]));
}

__global__ void finalize_kernel(const double* __restrict__ acc, float* __restrict__ out) {
    out[0] = (float)(acc[0] / 4194304.0);      // mean over N*N, N=2048
}

// ---------------------------------------------------------------- launch
extern "C" void kernel_launch(void* const* d_in, const int* in_sizes, int n_in,
                              void* d_out, int out_size, void* d_ws, size_t ws_size,
                              hipStream_t stream) {
    const float* src = (const float*)d_in[0];
    const float* tgt = (const float*)d_in[1];
    float* out = (float*)d_out;
    char* ws = (char*)d_ws;
    float*  L2   = (float*)(ws + L2_OFF);
    ushort* ahp  = (ushort*)(ws + AH_OFF);
    ushort* alp  = (ushort*)(ws + AL_OFF);
    float*  sq   = (float*)(ws + SQ_OFF);
    uint*   hist = (uint*)(ws + HIST_OFF);
    uint*   sel  = (uint*)(ws + SEL_OFF);
    double* acc  = (double*)(ws + ACC_OFF);

    hipMemsetAsync(ws + HIST_OFF, 0, 4096 + 32 + 16, stream);

    convert_kernel<<<MROWS, 256, 0, stream>>>(src, tgt, ahp, alp, sq);
    gemm_kernel<<<NTRI, 256, 0, stream>>>(ahp, alp, sq, L2);

    for (int p = 0; p < 4; ++p) {
        hist_kernel<<<2048, 256, 0, stream>>>(L2, hist + p * 256, sel, p);
        select_kernel<<<1, 256, 0, stream>>>(hist + p * 256, sel, out, p);
    }

    loss_kernel<<<2048, 256, 0, stream>>>(L2, (const float*)sel, acc);
    finalize_kernel<<<1, 1, 0, stream>>>(acc, out);
}